// Round 6
// baseline (118.900 us; speedup 1.0000x reference)
//
#include <hip/hip_runtime.h>

// pred_vol (1,1,64,512,512) fp32; thresh 0.5; 9x9x9 max-pool NMS.
// Identity: thr is monotone and the window contains the center, so
// reference output == (c > 0.5 && c == max999_raw(x)) ? c : 0.
//
// v6 = v5 pipeline (triple-buffered DMA staging, dist-2 prefetch, counted
// vmcnt barriers, C-ring centers, bcol + prefix/suffix horizontal, 8-slot
// D-ring) with TH=8: each thread owns TWO adjacent output rows, sharing an
// 8-row vertical core -> 10 LDS reads per 2 outputs (was 9 per 1).
// LDS ops/output-row: 45 -> 30. Grid 256 blocks, 112 KB LDS, 1 block/CU,
// launch_bounds(512,1) so the doubled R/C rings fit without spill.
// (R5 resubmit: prior round was an infra container failure; kernel audit
// found no hang/fault path — barriers uniform, vmcnt counts verified.)
static constexpr int Dd = 64;
static constexpr int Hh = 512;
static constexpr int Ww = 512;
static constexpr int RAD = 4;
static constexpr float THRESH_V = 0.5f;
static constexpr int W4 = Ww / 4;           // 128 float4 per row
static constexpr int PLANE4 = Hh * W4;      // 65536 float4 per D-plane

static constexpr int TH = 8;                // output h-rows per block
static constexpr int DC = 16;               // output d-planes per block
static constexpr int ROWS = TH + 2 * RAD;   // 16 staged raw rows per plane
static constexpr int NPL = DC + 2 * RAD;    // 24 d-steps per block
static constexpr int NBLK = (Hh / TH) * (Dd / DC);  // 64*4 = 256 blocks

typedef float nf4 __attribute__((ext_vector_type(4)));

__device__ __forceinline__ float4 f4max(float4 a, float4 b) {
    return make_float4(fmaxf(a.x, b.x), fmaxf(a.y, b.y), fmaxf(a.z, b.z), fmaxf(a.w, b.w));
}
__device__ __forceinline__ int iclamp(int v, int lo, int hi) {
    return v < lo ? lo : (v > hi ? hi : v);
}

// Counted-vmcnt barrier: drains this wave's stage(t) DMA group while newer
// prefetch groups and output stores stay in flight. lgkmcnt(0) orders LDS.
#define BAR_VM(N) asm volatile("s_waitcnt vmcnt(" #N ") lgkmcnt(0)\n\ts_barrier" ::: "memory")
// LDS-only barrier: publishes bcol writes without touching VMEM counters.
#define BAR_LDS() asm volatile("s_waitcnt lgkmcnt(0)\n\ts_barrier" ::: "memory")

// Direct global->LDS DMA, 16B per lane, dest = wave-uniform base + lane*16.
__device__ __forceinline__ void load_lds16(const float4* g, float4* l) {
    __builtin_amdgcn_global_load_lds(
        (const __attribute__((address_space(1))) void*)g,
        (__attribute__((address_space(3))) void*)l, 16, 0, 0);
}

// 112 KB LDS -> 1 block/CU regardless; min-blocks=1 frees the VGPR cap (256)
// so the doubled rings (R0/R1 + C0/C1 = 96 VGPR) fit without spilling.
__global__ __launch_bounds__(512, 1)
void fused_nms_k6(const float4* __restrict__ x4, float4* __restrict__ o4) {
    // 3 x 16-row raw buffers (96 KB) + 8-row col-max buffer (16 KB) = 112 KB
    __shared__ float4 braw[3][ROWS * W4];
    __shared__ float4 bcol[TH * W4];

    const int tid  = threadIdx.x;
    const int w4   = tid & (W4 - 1);   // 0..127
    const int hs   = tid >> 7;         // 0..3 row-pair slot (owns rows 2hs,2hs+1)
    const int wid  = tid >> 6;         // wave 0..7
    const int lane = tid & 63;

    // XCD swizzle: band = blockIdx&7 -> h-band stays on one XCD's L2
    const int b    = blockIdx.x;
    const int band = b & 7;
    const int rest = b >> 3;           // 0..31
    const int ht   = band * 8 + (rest & 7);   // 0..63
    const int dc   = rest >> 3;        // 0..3
    const int h0   = ht * TH;
    const int d0   = dc * DC;

    const int colm = w4 ? w4 - 1 : 0;
    const int colp = (w4 < W4 - 1) ? w4 + 1 : W4 - 1;

    // Staging: 32 segments (16 rows x 2 half-rows), 4 per wave.
    int goff[4], loff[4];
#pragma unroll
    for (int k = 0; k < 4; ++k) {
        const int s    = wid + 8 * k;          // 0..31
        const int row  = s >> 1;               // 0..15
        const int half = s & 1;                // 0/1
        const int gh   = iclamp(h0 - RAD + row, 0, Hh - 1);
        goff[k] = gh * W4 + half * 64 + lane;
        loff[k] = row * W4 + half * 64;
    }

    auto stage = [&](int p) {  // stage plane index p into braw[p % 3]
        const int gd = iclamp(d0 - RAD + p, 0, Dd - 1);
        const float4* pl = x4 + (size_t)gd * PLANE4;
        float4* dst = braw[p % 3];
#pragma unroll
        for (int k = 0; k < 4; ++k)
            load_lds16(pl + goff[k], dst + loff[k]);
    };

    // Horizontal 9-window from neighbor col-maxes via prefix/suffix.
    auto hwin = [&](const float4 lm, const float4 cm, const float4 rm) -> float4 {
        const float l3 = lm.w, l2 = fmaxf(lm.z, l3), l1 = fmaxf(lm.y, l2), l0 = fmaxf(lm.x, l1);
        const float core = fmaxf(fmaxf(cm.x, cm.y), fmaxf(cm.z, cm.w));
        const float q0 = rm.x, q1 = fmaxf(q0, rm.y), q2 = fmaxf(q1, rm.z), q3 = fmaxf(q2, rm.w);
        float4 pm;
        pm.x = fmaxf(l0, fmaxf(core, q0));
        pm.y = fmaxf(l1, fmaxf(core, q1));
        pm.z = fmaxf(l2, fmaxf(core, q2));
        pm.w = fmaxf(l3, fmaxf(core, q3));
        return pm;
    };

    // R: 8-slot ring of HxW-maxed rows (x2 owned rows). C: 4-slot center
    // ring — output plane d0+t-8 has plane-index t-4, whose vertical ran at
    // step t-4 (wrote C[(t-4)&3] == C[t&3]); read at t before overwrite.
    float4 R0[8], R1[8];
    float4 C0[4], C1[4];

    // Prologue: planes 0,1 staged; in-loop stage(t+2) covers 2..23.
    stage(0);
    stage(1);

    // 24 steps, fully unrolled: all parities/slots/vmcnt counts are static.
#pragma unroll
    for (int t = 0; t < NPL; ++t) {
        const bool doE = (t >= 8);   // emit output plane d0 + t - 8

        // Drain stage(t) (issued at step t-2; 4 ops/wave). Ops issued after
        // it per wave: store(t-2) x2 [t>=10], stage(t+1) x4 [t<=22],
        // store(t-1) x2 [t>=9]. No other in-loop global loads exist.
        if (t <= 8)       { BAR_VM(4); }
        else if (t == 9)  { BAR_VM(6); }
        else if (t <= 22) { BAR_VM(8); }
        else              { BAR_VM(4); }

        // Distance-2 prefetch: ~2 full steps in flight.
        if (t + 2 < NPL) stage(t + 2);
        __builtin_amdgcn_sched_barrier(0);

        // Vertical: staged rows 2hs..2hs+9 (10 reads), shared 8-row core
        // serving both owned windows. r4/r5 are the raw centers of the two
        // owned rows for this step's plane.
        const float4* Bc = &braw[t % 3][(2 * hs) * W4 + w4];
        float4 r0 = Bc[0 * W4], r1 = Bc[1 * W4], r2 = Bc[2 * W4], r3 = Bc[3 * W4];
        float4 r4 = Bc[4 * W4], r5 = Bc[5 * W4], r6 = Bc[6 * W4], r7 = Bc[7 * W4];
        float4 r8 = Bc[8 * W4], r9 = Bc[9 * W4];
        float4 core = f4max(f4max(f4max(r1, r2), f4max(r3, r4)),
                            f4max(f4max(r5, r6), f4max(r7, r8)));
        float4 v0 = f4max(core, r0);   // rows 2hs .. 2hs+8
        float4 v1 = f4max(core, r9);   // rows 2hs+1 .. 2hs+9
        bcol[(2 * hs) * W4 + w4]     = v0;
        bcol[(2 * hs + 1) * W4 + w4] = v1;
        BAR_LDS();

        const float4 pm0 = hwin(bcol[(2 * hs) * W4 + colm],     v0, bcol[(2 * hs) * W4 + colp]);
        const float4 pm1 = hwin(bcol[(2 * hs + 1) * W4 + colm], v1, bcol[(2 * hs + 1) * W4 + colp]);

        // Emit: D-window-9 = max(8 ring slots, current pm); centers from C.
        if (doE) {
            const float4 cen0 = C0[t & 3];   // written at step t-4
            const float4 cen1 = C1[t & 3];
            float4 mm0 = pm0, mm1 = pm1;
#pragma unroll
            for (int i = 0; i < 8; ++i) { mm0 = f4max(mm0, R0[i]); mm1 = f4max(mm1, R1[i]); }
            const size_t obase = (size_t)(d0 + t - 8) * PLANE4 + (size_t)(h0 + 2 * hs) * W4 + w4;
            nf4 q0, q1;
            q0.x = (cen0.x > THRESH_V && cen0.x == mm0.x) ? cen0.x : 0.0f;
            q0.y = (cen0.y > THRESH_V && cen0.y == mm0.y) ? cen0.y : 0.0f;
            q0.z = (cen0.z > THRESH_V && cen0.z == mm0.z) ? cen0.z : 0.0f;
            q0.w = (cen0.w > THRESH_V && cen0.w == mm0.w) ? cen0.w : 0.0f;
            q1.x = (cen1.x > THRESH_V && cen1.x == mm1.x) ? cen1.x : 0.0f;
            q1.y = (cen1.y > THRESH_V && cen1.y == mm1.y) ? cen1.y : 0.0f;
            q1.z = (cen1.z > THRESH_V && cen1.z == mm1.z) ? cen1.z : 0.0f;
            q1.w = (cen1.w > THRESH_V && cen1.w == mm1.w) ? cen1.w : 0.0f;
            __builtin_nontemporal_store(q0, (nf4*)&o4[obase]);
            __builtin_nontemporal_store(q1, (nf4*)&o4[obase + W4]);
        }
        R0[t & 7] = pm0;  R1[t & 7] = pm1;   // overwrite after use
        C0[t & 3] = r4;   C1[t & 3] = r5;    // overwrite after read
    }
}

extern "C" void kernel_launch(void* const* d_in, const int* in_sizes, int n_in,
                              void* d_out, int out_size, void* d_ws, size_t ws_size,
                              hipStream_t stream) {
    const float4* x4 = (const float4*)d_in[0];
    float4* out4 = (float4*)d_out;
    (void)d_ws; (void)ws_size; (void)in_sizes; (void)n_in; (void)out_size;
    fused_nms_k6<<<dim3(NBLK), dim3(512), 0, stream>>>(x4, out4);
}

// Round 7
// 116.110 us; speedup vs baseline: 1.0240x; 1.0240x over previous
//
#include <hip/hip_runtime.h>

// pred_vol (1,1,64,512,512) fp32; thresh 0.5; 9x9x9 max-pool NMS.
// Identity: thr is monotone and the window contains the center, so
// reference output == (c > 0.5 && c == max999_raw(x)) ? c : 0.
//
// v7 = v6 (TH=8 row-pair vertical sharing, triple-buffered DMA staging,
// dist-2 prefetch, counted vmcnt, C-ring centers, 8-slot D-ring) with the
// two per-step barriers MERGED into one: vert(t) || horiz+emit(t-1) with
// double-buffered bcol. Barriers/block 48 -> 25; vert LDS reads and
// horiz/emit VALU interleave in one phase (ILP for the 2-wave/SIMD regime).
// Pipeline shift: pm(p) computed at step p+1; emit plane j at step j+9;
// centers ride a depth-5 ring (read slot == write slot, read first).
static constexpr int Dd = 64;
static constexpr int Hh = 512;
static constexpr int Ww = 512;
static constexpr int RAD = 4;
static constexpr float THRESH_V = 0.5f;
static constexpr int W4 = Ww / 4;           // 128 float4 per row
static constexpr int PLANE4 = Hh * W4;      // 65536 float4 per D-plane

static constexpr int TH = 8;                // output h-rows per block
static constexpr int DC = 16;               // output d-planes per block
static constexpr int ROWS = TH + 2 * RAD;   // 16 staged raw rows per plane
static constexpr int NPL = DC + 2 * RAD;    // 24 planes; loop runs t=0..24
static constexpr int NBLK = (Hh / TH) * (Dd / DC);  // 256 blocks (1/CU)

typedef float nf4 __attribute__((ext_vector_type(4)));

__device__ __forceinline__ float4 f4max(float4 a, float4 b) {
    return make_float4(fmaxf(a.x, b.x), fmaxf(a.y, b.y), fmaxf(a.z, b.z), fmaxf(a.w, b.w));
}
__device__ __forceinline__ int iclamp(int v, int lo, int hi) {
    return v < lo ? lo : (v > hi ? hi : v);
}

// Counted-vmcnt barrier: drains this wave's stage(t) DMA group while newer
// prefetch groups and output stores stay in flight. lgkmcnt(0) orders LDS.
#define BAR_VM(N) asm volatile("s_waitcnt vmcnt(" #N ") lgkmcnt(0)\n\ts_barrier" ::: "memory")
// LDS-only barrier (final step: nothing to drain but bcol publication).
#define BAR_LDS() asm volatile("s_waitcnt lgkmcnt(0)\n\ts_barrier" ::: "memory")

// Direct global->LDS DMA, 16B per lane, dest = wave-uniform base + lane*16.
__device__ __forceinline__ void load_lds16(const float4* g, float4* l) {
    __builtin_amdgcn_global_load_lds(
        (const __attribute__((address_space(1))) void*)g,
        (__attribute__((address_space(3))) void*)l, 16, 0, 0);
}

// 128 KB LDS -> 1 block/CU; min-blocks=1 keeps the 256-VGPR cap so the
// rings (R 64 + C 40 VGPR) and the 10-row vertical live set fit unspilled.
__global__ __launch_bounds__(512, 1)
void fused_nms_k7(const float4* __restrict__ x4, float4* __restrict__ o4) {
    // 3 x 16-row raw buffers (96 KB) + 2 x 8-row col-max buffers (32 KB)
    __shared__ float4 braw[3][ROWS * W4];
    __shared__ float4 bcol[2][TH * W4];

    const int tid  = threadIdx.x;
    const int w4   = tid & (W4 - 1);   // 0..127
    const int hs   = tid >> 7;         // 0..3 row-pair slot (owns rows 2hs,2hs+1)
    const int wid  = tid >> 6;         // wave 0..7
    const int lane = tid & 63;

    // XCD swizzle: band = blockIdx&7 -> h-band stays on one XCD's L2
    const int b    = blockIdx.x;
    const int band = b & 7;
    const int rest = b >> 3;           // 0..31
    const int ht   = band * 8 + (rest & 7);   // 0..63
    const int dc   = rest >> 3;        // 0..3
    const int h0   = ht * TH;
    const int d0   = dc * DC;

    const int colm = w4 ? w4 - 1 : 0;
    const int colp = (w4 < W4 - 1) ? w4 + 1 : W4 - 1;

    // Staging: 32 segments (16 rows x 2 half-rows), 4 per wave.
    int goff[4], loff[4];
#pragma unroll
    for (int k = 0; k < 4; ++k) {
        const int s    = wid + 8 * k;          // 0..31
        const int row  = s >> 1;               // 0..15
        const int half = s & 1;                // 0/1
        const int gh   = iclamp(h0 - RAD + row, 0, Hh - 1);
        goff[k] = gh * W4 + half * 64 + lane;
        loff[k] = row * W4 + half * 64;
    }

    auto stage = [&](int p) {  // stage plane index p into braw[p % 3]
        const int gd = iclamp(d0 - RAD + p, 0, Dd - 1);
        const float4* pl = x4 + (size_t)gd * PLANE4;
        float4* dst = braw[p % 3];
#pragma unroll
        for (int k = 0; k < 4; ++k)
            load_lds16(pl + goff[k], dst + loff[k]);
    };

    // Horizontal 9-window from neighbor col-maxes via prefix/suffix.
    auto hwin = [&](const float4 lm, const float4 cm, const float4 rm) -> float4 {
        const float l3 = lm.w, l2 = fmaxf(lm.z, l3), l1 = fmaxf(lm.y, l2), l0 = fmaxf(lm.x, l1);
        const float core = fmaxf(fmaxf(cm.x, cm.y), fmaxf(cm.z, cm.w));
        const float q0 = rm.x, q1 = fmaxf(q0, rm.y), q2 = fmaxf(q1, rm.z), q3 = fmaxf(q2, rm.w);
        float4 pm;
        pm.x = fmaxf(l0, fmaxf(core, q0));
        pm.y = fmaxf(l1, fmaxf(core, q1));
        pm.z = fmaxf(l2, fmaxf(core, q2));
        pm.w = fmaxf(l3, fmaxf(core, q3));
        return pm;
    };

    // R: 8-slot ring of pm (HxW-maxed rows). At step t the ring holds
    // pm(t-9..t-2); with this step's pm(t-1) that is the 9-plane D-window
    // for output plane j = t-9 (absolute d = d0+t-9).
    // C: depth-5 center ring; read C[t%5] (written at step t-5 = plane
    // index of the emitted output) before overwriting with plane t's.
    float4 R0[8], R1[8];
    float4 C0[5], C1[5];
    float4 vp0, vp1;   // vert results of plane t-1 (own column)

    // Prologue: planes 0,1 staged; in-loop stage(t+2) covers 2..23.
    stage(0);
    stage(1);

    // 25 steps, fully unrolled: all parities/slots/vmcnt counts are static.
#pragma unroll
    for (int t = 0; t <= NPL; ++t) {
        const bool doV = (t <= NPL - 1);   // vertical for plane t (0..23)
        const bool doH = (t >= 1);         // horiz+ring for plane t-1
        const bool doE = (t >= 9);         // emit output plane d0 + t - 9

        // ONE barrier per step: publishes bcol(t-1) writes AND drains
        // stage(t) (issued at step t-2; 4 DMA ops/wave). Per-wave VMEM ops
        // issued after stage(t): stores(t-2) x2 [t>=11], stage(t+1) x4
        // [t<=22], stores(t-1) x2 [t>=10].
        if (t <= 9)       { BAR_VM(4); }
        else if (t == 10) { BAR_VM(6); }
        else if (t <= 22) { BAR_VM(8); }
        else if (t == 23) { BAR_VM(4); }
        else              { BAR_LDS(); }

        // Distance-2 prefetch: ~2 full steps in flight.
        if (t + 2 <= NPL - 1) stage(t + 2);
        __builtin_amdgcn_sched_barrier(0);

        // ---- vertical for plane t: staged rows 2hs..2hs+9 (10 reads),
        //      shared 8-row core serving both owned windows.
        float4 nv0, nv1, nc0, nc1;
        if (doV) {
            const float4* Bc = &braw[t % 3][(2 * hs) * W4 + w4];
            float4 r0 = Bc[0 * W4], r1 = Bc[1 * W4], r2 = Bc[2 * W4], r3 = Bc[3 * W4];
            float4 r4 = Bc[4 * W4], r5 = Bc[5 * W4], r6 = Bc[6 * W4], r7 = Bc[7 * W4];
            float4 r8 = Bc[8 * W4], r9 = Bc[9 * W4];
            float4 core = f4max(f4max(f4max(r1, r2), f4max(r3, r4)),
                                f4max(f4max(r5, r6), f4max(r7, r8)));
            nv0 = f4max(core, r0);   // rows 2hs .. 2hs+8
            nv1 = f4max(core, r9);   // rows 2hs+1 .. 2hs+9
            bcol[t & 1][(2 * hs) * W4 + w4]     = nv0;
            bcol[t & 1][(2 * hs + 1) * W4 + w4] = nv1;
            nc0 = r4;   // raw center, global row h0+2hs
            nc1 = r5;   // raw center, global row h0+2hs+1
        }

        // ---- horizontal + D-ring + emit for plane t-1 (bcol published by
        //      this step's top barrier; own col-max still in vp0/vp1).
        if (doH) {
            const float4* Bp = &bcol[(t - 1) & 1][0];
            const float4 pm0 = hwin(Bp[(2 * hs) * W4 + colm],     vp0, Bp[(2 * hs) * W4 + colp]);
            const float4 pm1 = hwin(Bp[(2 * hs + 1) * W4 + colm], vp1, Bp[(2 * hs + 1) * W4 + colp]);

            if (doE) {
                const float4 cen0 = C0[t % 5];   // plane t-5 == emitted plane
                const float4 cen1 = C1[t % 5];
                float4 mm0 = pm0, mm1 = pm1;
#pragma unroll
                for (int i = 0; i < 8; ++i) { mm0 = f4max(mm0, R0[i]); mm1 = f4max(mm1, R1[i]); }
                const size_t obase = (size_t)(d0 + t - 9) * PLANE4
                                   + (size_t)(h0 + 2 * hs) * W4 + w4;
                nf4 q0, q1;
                q0.x = (cen0.x > THRESH_V && cen0.x == mm0.x) ? cen0.x : 0.0f;
                q0.y = (cen0.y > THRESH_V && cen0.y == mm0.y) ? cen0.y : 0.0f;
                q0.z = (cen0.z > THRESH_V && cen0.z == mm0.z) ? cen0.z : 0.0f;
                q0.w = (cen0.w > THRESH_V && cen0.w == mm0.w) ? cen0.w : 0.0f;
                q1.x = (cen1.x > THRESH_V && cen1.x == mm1.x) ? cen1.x : 0.0f;
                q1.y = (cen1.y > THRESH_V && cen1.y == mm1.y) ? cen1.y : 0.0f;
                q1.z = (cen1.z > THRESH_V && cen1.z == mm1.z) ? cen1.z : 0.0f;
                q1.w = (cen1.w > THRESH_V && cen1.w == mm1.w) ? cen1.w : 0.0f;
                __builtin_nontemporal_store(q0, (nf4*)&o4[obase]);
                __builtin_nontemporal_store(q1, (nf4*)&o4[obase + W4]);
            }
            R0[(t - 1) & 7] = pm0;   // overwrite after use
            R1[(t - 1) & 7] = pm1;
        }

        // ---- roll per-step registers (after all reads of the old values).
        if (doV) {
            vp0 = nv0;  vp1 = nv1;
            C0[t % 5] = nc0;  C1[t % 5] = nc1;   // slot read above first
        }
    }
}

extern "C" void kernel_launch(void* const* d_in, const int* in_sizes, int n_in,
                              void* d_out, int out_size, void* d_ws, size_t ws_size,
                              hipStream_t stream) {
    const float4* x4 = (const float4*)d_in[0];
    float4* out4 = (float4*)d_out;
    (void)d_ws; (void)ws_size; (void)in_sizes; (void)n_in; (void)out_size;
    fused_nms_k7<<<dim3(NBLK), dim3(512), 0, stream>>>(x4, out4);
}